// Round 3
// baseline (64.778 us; speedup 1.0000x reference)
//
#include <hip/hip_runtime.h>
#include <hip/hip_bf16.h>

// Problem constants (B=1, N=1024, D=128, H=8, HD=32 -> 2D = 256 weight elems)
#define NN 1024
#define DD 128

// Algebra (derived from the concat(axis=0)+reshape trace):
//   U[r] = dot(inp[r], w[0:128]),  V[r] = dot(inp[r], w[128:256])
//   m <  512: raw[m][n] = U[2m+(n>=512)] + V[2m+(n>=512)]
//   m >= 512: raw[m][n] = U[2j] + V[2j+1],  j = n & 511   (row-invariant)
// Since masked value is 0 -> exp(0)=1, precompute the ONLY exp values needed:
//   eA[r] = exp(lrelu(U[r]+V[r]))            (low row m uses eA[2m], eA[2m+1])
//   eH[j] = exp(lrelu(U[2j]+V[2j+1]))        (shared by every high row)
// row kernel then just selects eX vs 1.0 per adj and normalizes.

__global__ void __launch_bounds__(128)
prep_kernel(const float* __restrict__ inp,
            const float* __restrict__ w,
            float* __restrict__ eA,
            float* __restrict__ eH) {
    const int r = blockIdx.x * 128 + threadIdx.x;   // 0..1023, one row per thread
    const float4* row = (const float4*)(inp + r * DD);
    const float4* wu4 = (const float4*)w;           // uniform addresses
    const float4* wv4 = (const float4*)(w + DD);
    float u = 0.f, v = 0.f;
    #pragma unroll
    for (int k = 0; k < DD / 4; ++k) {
        const float4 x  = row[k];
        const float4 wu = wu4[k];
        const float4 wv = wv4[k];
        u += x.x * wu.x + x.y * wu.y + x.z * wu.z + x.w * wu.w;
        v += x.x * wv.x + x.y * wv.y + x.z * wv.z + x.w * wv.w;
    }
    // low-row value for row r
    float slo = u + v;
    slo = (slo >= 0.f) ? slo : 0.01f * slo;
    eA[r] = __expf(slo);
    // high-row value for pair j = r>>1: z[2j] + z[2j+1], z[r] = odd ? V : U
    const float zr = (r & 1) ? v : u;
    const float zp = __shfl_xor(zr, 1);
    float shi = zr + zp;
    shi = (shi >= 0.f) ? shi : 0.01f * shi;
    if ((r & 1) == 0) eH[r >> 1] = __expf(shi);
}

// One block (256 threads) per output row m; thread t owns columns 4t..4t+3.
// No transcendentals here: select precomputed exp (adj=1) vs 1.0 (adj=0).
__global__ void __launch_bounds__(256)
row_kernel(const int* __restrict__ adj,
           const float* __restrict__ eA,
           const float* __restrict__ eH,
           float* __restrict__ out) {
    const int m = blockIdx.x;
    const int t = threadIdx.x;          // 0..255

    const int4 a4 = ((const int4*)(adj + m * NN))[t];

    float e[4];
    if (m < 512) {
        // columns 4t..4t+3 all in same half (boundary at t==128, wave-uniform)
        const float ea = (t < 128) ? eA[2 * m] : eA[2 * m + 1];
        e[0] = (a4.x > 0) ? ea : 1.0f;
        e[1] = (a4.y > 0) ? ea : 1.0f;
        e[2] = (a4.z > 0) ? ea : 1.0f;
        e[3] = (a4.w > 0) ? ea : 1.0f;
    } else {
        const float4 eh = ((const float4*)eH)[t & 127];
        e[0] = (a4.x > 0) ? eh.x : 1.0f;
        e[1] = (a4.y > 0) ? eh.y : 1.0f;
        e[2] = (a4.z > 0) ? eh.z : 1.0f;
        e[3] = (a4.w > 0) ? eh.w : 1.0f;
    }

    float s = (e[0] + e[1]) + (e[2] + e[3]);
    #pragma unroll
    for (int off = 32; off > 0; off >>= 1) s += __shfl_down(s, off);
    __shared__ float sm[4];
    if ((t & 63) == 0) sm[t >> 6] = s;
    __syncthreads();
    const float inv = 1.0f / ((sm[0] + sm[1]) + (sm[2] + sm[3]));

    float4 o;
    o.x = e[0] * inv; o.y = e[1] * inv; o.z = e[2] * inv; o.w = e[3] * inv;
    ((float4*)(out + m * NN))[t] = o;
}

extern "C" void kernel_launch(void* const* d_in, const int* in_sizes, int n_in,
                              void* d_out, int out_size, void* d_ws, size_t ws_size,
                              hipStream_t stream) {
    const float* inp = (const float*)d_in[0];   // (1,1024,128) fp32
    const int*   adj = (const int*)d_in[1];     // (1,1024,1024) int32
    const float* w   = (const float*)d_in[2];   // (8,32,1)x2 fp32 -> flat 256
    float* out = (float*)d_out;                 // (1,1024,1024) fp32

    float* eA = (float*)d_ws;        // 1024 floats
    float* eH = eA + NN;             // 512 floats

    prep_kernel<<<NN / 128, 128, 0, stream>>>(inp, w, eA, eH);
    row_kernel<<<NN, 256, 0, stream>>>(adj, eA, eH, out);
}